// Round 1
// baseline (160.838 us; speedup 1.0000x reference)
//
#include <hip/hip_runtime.h>

// One block per row. N = 4096 floats/row.
// Pass 1: stage row in LDS (16 KiB) + count {0,1} occurrences.
// Pass 2: fill invalid (-1) with row mode, emit (1-v, v) pairs.
// Rows with no valid entries: every entry is -1, and reference outputs all-1;
// setting mode=1 in that case makes the fill path produce exactly that.

__global__ __launch_bounds__(256) void StatsMode_kernel(
    const float* __restrict__ X, float* __restrict__ out, int nvec /* N/4 */) {
  __shared__ float4 srow[1024];   // 16 KiB: one row (N=4096 floats)
  __shared__ int red0[4], red1[4];

  const int row  = blockIdx.x;
  const int tid  = threadIdx.x;
  const float4* xrow = reinterpret_cast<const float4*>(X) + (size_t)row * nvec;

  int c0 = 0, c1 = 0;
  for (int i = tid; i < nvec; i += 256) {
    float4 v = xrow[i];
    srow[i] = v;
    c0 += (v.x == 0.0f) + (v.y == 0.0f) + (v.z == 0.0f) + (v.w == 0.0f);
    c1 += (v.x == 1.0f) + (v.y == 1.0f) + (v.z == 1.0f) + (v.w == 1.0f);
  }

  // wave-level reduce (64 lanes)
  #pragma unroll
  for (int off = 32; off > 0; off >>= 1) {
    c0 += __shfl_down(c0, off, 64);
    c1 += __shfl_down(c1, off, 64);
  }
  const int wave = tid >> 6;
  const int lane = tid & 63;
  if (lane == 0) { red0[wave] = c0; red1[wave] = c1; }
  __syncthreads();

  const int t0 = red0[0] + red0[1] + red0[2] + red0[3];
  const int t1 = red1[0] + red1[1] + red1[2] + red1[3];
  // tie -> 0 (count1 > count0 required for 1); no valid entries -> 1
  const float mode = ((t0 + t1) == 0) ? 1.0f : ((t1 > t0) ? 1.0f : 0.0f);

  float4* orow = reinterpret_cast<float4*>(out) + (size_t)row * (nvec * 2);
  for (int i = tid; i < nvec; i += 256) {
    float4 v = srow[i];
    const float a = (v.x == -1.0f) ? mode : v.x;
    const float b = (v.y == -1.0f) ? mode : v.y;
    const float c = (v.z == -1.0f) ? mode : v.z;
    const float d = (v.w == -1.0f) ? mode : v.w;
    orow[i * 2]     = make_float4(1.0f - a, a, 1.0f - b, b);
    orow[i * 2 + 1] = make_float4(1.0f - c, c, 1.0f - d, d);
  }
}

extern "C" void kernel_launch(void* const* d_in, const int* in_sizes, int n_in,
                              void* d_out, int out_size, void* d_ws, size_t ws_size,
                              hipStream_t stream) {
  const float* X = (const float*)d_in[0];
  float* out = (float*)d_out;
  const int N = 4096;
  const int B = in_sizes[0] / N;          // 16384
  StatsMode_kernel<<<B, 256, 0, stream>>>(X, out, N / 4);
}

// Round 3
// 143.391 us; speedup vs baseline: 1.1217x; 1.1217x over previous
//
#include <hip/hip_runtime.h>

// One block per row, N = 4096 hardcoded.
// Pass 1: nontemporal f32x4 loads -> LDS + count {0,1}.
// Pass 2: lane j reads f32x2 from LDS, emits ONE contiguous f32x4 (1-v, v)
//         pair-vector via nontemporal store -> every store instruction is a
//         dense wave-contiguous 1 KiB burst (was: 2 stores strided 32 B).

typedef float f32x4 __attribute__((ext_vector_type(4)));
typedef float f32x2 __attribute__((ext_vector_type(2)));

constexpr int kN    = 4096;
constexpr int kNV4  = kN / 4;   // 1024 input float4 per row
constexpr int kNO4  = kN / 2;   // 2048 output float4 per row

__global__ __launch_bounds__(256) void StatsMode_kernel(
    const float* __restrict__ X, float* __restrict__ out) {
  __shared__ float srow[kN];      // 16 KiB
  __shared__ int red0[4], red1[4];

  const int row = blockIdx.x;
  const int tid = threadIdx.x;
  const f32x4* xrow = reinterpret_cast<const f32x4*>(X) + (size_t)row * kNV4;

  int c0 = 0, c1 = 0;
  f32x4* srow4 = reinterpret_cast<f32x4*>(srow);
  #pragma unroll
  for (int k = 0; k < kNV4 / 256; ++k) {
    const int i = tid + k * 256;
    f32x4 v = __builtin_nontemporal_load(&xrow[i]);
    srow4[i] = v;
    c0 += (v.x == 0.0f) + (v.y == 0.0f) + (v.z == 0.0f) + (v.w == 0.0f);
    c1 += (v.x == 1.0f) + (v.y == 1.0f) + (v.z == 1.0f) + (v.w == 1.0f);
  }

  // wave-level reduce (64 lanes)
  #pragma unroll
  for (int off = 32; off > 0; off >>= 1) {
    c0 += __shfl_down(c0, off, 64);
    c1 += __shfl_down(c1, off, 64);
  }
  const int wave = tid >> 6;
  if ((tid & 63) == 0) { red0[wave] = c0; red1[wave] = c1; }
  __syncthreads();

  const int t0 = red0[0] + red0[1] + red0[2] + red0[3];
  const int t1 = red1[0] + red1[1] + red1[2] + red1[3];
  // tie -> 0; no valid entries -> all entries are -1 and mode=1 reproduces
  // the reference's all-ones row.
  const float mode = ((t0 + t1) == 0) ? 1.0f : ((t1 > t0) ? 1.0f : 0.0f);

  f32x4* orow = reinterpret_cast<f32x4*>(out) + (size_t)row * kNO4;
  const f32x2* srow2 = reinterpret_cast<const f32x2*>(srow);
  #pragma unroll
  for (int k = 0; k < kNO4 / 256; ++k) {
    const int j = tid + k * 256;
    f32x2 v = srow2[j];
    const float a = (v.x == -1.0f) ? mode : v.x;
    const float b = (v.y == -1.0f) ? mode : v.y;
    f32x4 o; o.x = 1.0f - a; o.y = a; o.z = 1.0f - b; o.w = b;
    __builtin_nontemporal_store(o, &orow[j]);
  }
}

extern "C" void kernel_launch(void* const* d_in, const int* in_sizes, int n_in,
                              void* d_out, int out_size, void* d_ws, size_t ws_size,
                              hipStream_t stream) {
  const float* X = (const float*)d_in[0];
  float* out = (float*)d_out;
  const int B = in_sizes[0] / kN;   // 16384
  StatsMode_kernel<<<B, 256, 0, stream>>>(X, out);
}